// Round 7
// baseline (115.364 us; speedup 1.0000x reference)
//
#include <hip/hip_runtime.h>
#include <stdint.h>

// Problem constants (fixed by setup_inputs)
#define TOKENS 64
#define IN_F   4096
#define OUT_F  11008
#define RANK   16
#define GS     128
#define NG     32
#define ZCOLS  (OUT_F / 8)
#define LORA_SCALE 2.0f
#define BN 32                 // columns per block

using short8  = __attribute__((ext_vector_type(8))) short;
using float4v = __attribute__((ext_vector_type(4))) float;

// round-to-nearest-even fp32 -> bf16 bits; also returns the rounded-back fp32
static __device__ inline uint16_t f2bf(float f, float* back) {
    uint32_t u = __float_as_uint(f);
    uint32_t r = (u + 0x7FFFu + ((u >> 16) & 1u)) >> 16;
    *back = __uint_as_float(r << 16);
    return (uint16_t)r;
}

// ---------------------------------------------------------------------------
// K1: per token t (64 blocks):
//   xf (MFMA-fragment order) = bf16(x)   — xf4[(m*128 + kchunk)*64 + quad*16 + n]
//     holds token (m*16+n), k in [kchunk*32 + quad*8, +8): one uint4 = 8 bf16.
//   xsumT[g][t] = sum over group g of bf16-rounded x   (GPTQ zero fold)
//   midT[j][t]  = sum_k x[t][k] * lora_A[j][k]         (fp32 LoRA mid)
// ---------------------------------------------------------------------------
__global__ __launch_bounds__(256) void prep_kernel(
        const float* __restrict__ x,
        const float* __restrict__ loraA,
        uint4* __restrict__ xf4,
        float* __restrict__ xsumT,
        float* __restrict__ midT) {
    __shared__ float redg[256];
    __shared__ float redm[4][16];
    const int t    = blockIdx.x;
    const int tid  = threadIdx.x;
    const int lane = tid & 63;
    const int wv   = tid >> 6;

    float4 xv[4];
    const float4* xp = (const float4*)(x + (size_t)t * IN_F + tid * 16);
    #pragma unroll
    for (int i = 0; i < 4; ++i) xv[i] = xp[i];

    union { uint16_t u[16]; uint4 q[2]; } ob;
    float s = 0.f;
    #pragma unroll
    for (int i = 0; i < 4; ++i) {
        float b;
        ob.u[i * 4 + 0] = f2bf(xv[i].x, &b); s += b;
        ob.u[i * 4 + 1] = f2bf(xv[i].y, &b); s += b;
        ob.u[i * 4 + 2] = f2bf(xv[i].z, &b); s += b;
        ob.u[i * 4 + 3] = f2bf(xv[i].w, &b); s += b;
    }
    // scatter into fragment order
    {
        const int mm = t >> 4, nn = t & 15;
        const int kchunk = tid >> 1;
        #pragma unroll
        for (int i = 0; i < 2; ++i) {
            const int qd = (tid * 2 + i) & 3;
            xf4[(size_t)((mm * 128 + kchunk) * 64 + qd * 16 + nn)] = ob.q[i];
        }
    }
    redg[tid] = s;

    // LoRA mid partials
    float pj[16];
    #pragma unroll
    for (int j = 0; j < 16; ++j) {
        const float4* ap = (const float4*)(loraA + (size_t)j * IN_F + tid * 16);
        float ps = 0.f;
        #pragma unroll
        for (int i = 0; i < 4; ++i) {
            float4 a = ap[i];
            ps += a.x * xv[i].x + a.y * xv[i].y + a.z * xv[i].z + a.w * xv[i].w;
        }
        pj[j] = ps;
    }
    #pragma unroll
    for (int j = 0; j < 16; ++j) {
        #pragma unroll
        for (int off = 32; off; off >>= 1) pj[j] += __shfl_down(pj[j], off);
    }
    if (lane == 0) {
        #pragma unroll
        for (int j = 0; j < 16; ++j) redm[wv][j] = pj[j];
    }
    __syncthreads();
    if (tid < NG) {
        float g = 0.f;
        #pragma unroll
        for (int i = 0; i < 8; ++i) g += redg[tid * 8 + i];
        xsumT[tid * TOKENS + t] = g;
    }
    if (tid < 16)
        midT[tid * TOKENS + t] = redm[0][tid] + redm[1][tid] + redm[2][tid] + redm[3][tid];
}

// ---------------------------------------------------------------------------
// K2: fused GPTQ-dequant GEMM + LoRA epilogue. ZERO LDS, ZERO barriers.
// Block 256 = 4 free-running waves (wave = M-tile x 32 cols, full K); the 4
// waves share qweight through L1/L2. Software pipeline: B (HBM stream,
// ~900 cyc) ring depth 4; A-frags / xsum / scales / zeros (L2-hot) depth 2.
// Dequant via 0x4300 trick (bf16(128+q)); per-group fold removes
// (zero+1+128)*xsum and applies scale. Outputs stored exactly once.
// ---------------------------------------------------------------------------
#define LOADB(sb, g) do {                                                      \
    _Pragma("unroll")                                                          \
    for (int ks = 0; ks < 4; ++ks) {                                           \
        B[sb][ks * 2]     = qwc[(size_t)((g) * 16 + ks * 4 + quad) * OUT_F];   \
        B[sb][ks * 2 + 1] = qwc[(size_t)((g) * 16 + ks * 4 + quad) * OUT_F + 16];\
    }                                                                          \
} while (0)

#define LOADA(sa, g) do {                                                      \
    _Pragma("unroll")                                                          \
    for (int ks = 0; ks < 4; ++ks) A[sa][ks] = xfw[((g) * 4 + ks) * 64];       \
    XS[sa] = *(const float4*)(xsumT + (g) * 64 + m * 16 + quad * 4);           \
    S0[sa] = scales[(size_t)(g) * OUT_F + col0 + n];                           \
    S1[sa] = scales[(size_t)(g) * OUT_F + col0 + 16 + n];                      \
    Z0[sa] = qz[(size_t)(g) * ZCOLS + ((col0 + n) >> 3)];                      \
    Z1[sa] = qz[(size_t)(g) * ZCOLS + ((col0 + 16 + n) >> 3)];                 \
} while (0)

#define COMPUTE(sa, sb) do {                                                   \
    float4v accg0 = (float4v){0.f, 0.f, 0.f, 0.f};                             \
    float4v accg1 = (float4v){0.f, 0.f, 0.f, 0.f};                             \
    _Pragma("unroll")                                                          \
    for (int ks = 0; ks < 4; ++ks) {                                           \
        union { uint4 u; short8 s; } afu; afu.u = A[sa][ks];                   \
        _Pragma("unroll")                                                      \
        for (int nh = 0; nh < 2; ++nh) {                                       \
            uint32_t q  = B[sb][ks * 2 + nh];                                  \
            uint32_t lo = q & 0x0F0F0F0Fu;                                     \
            uint32_t hi = (q >> 4) & 0x0F0F0F0Fu;                              \
            union { uint32_t u32[4]; short8 s8; } bf;                          \
            _Pragma("unroll")                                                  \
            for (int i = 0; i < 4; ++i)                                        \
                bf.u32[i] = __builtin_amdgcn_perm(hi, lo,                      \
                                0x0C040C00u + i * 0x00010001u) | 0x43004300u;  \
            if (nh == 0)                                                       \
                accg0 = __builtin_amdgcn_mfma_f32_16x16x32_bf16(afu.s, bf.s8,  \
                                                                accg0, 0, 0, 0);\
            else                                                               \
                accg1 = __builtin_amdgcn_mfma_f32_16x16x32_bf16(afu.s, bf.s8,  \
                                                                accg1, 0, 0, 0);\
        }                                                                      \
    }                                                                          \
    const float zoff0 = (float)(((Z0[sa] >> (((col0 + n) & 7) * 4)) & 0xFu) + 129u);\
    const float zoff1 = (float)(((Z1[sa] >> (((col0 + 16 + n) & 7) * 4)) & 0xFu) + 129u);\
    const float4 xvv = XS[sa];                                                 \
    const float xvr[4] = {xvv.x, xvv.y, xvv.z, xvv.w};                         \
    _Pragma("unroll")                                                          \
    for (int r = 0; r < 4; ++r) {                                              \
        acc[0][r] = fmaf(S0[sa], fmaf(-zoff0, xvr[r], accg0[r]), acc[0][r]);   \
        acc[1][r] = fmaf(S1[sa], fmaf(-zoff1, xvr[r], accg1[r]), acc[1][r]);   \
    }                                                                          \
} while (0)

__global__ __launch_bounds__(256) void main_kernel(
        const uint32_t* __restrict__ qw,
        const uint32_t* __restrict__ qz,
        const float* __restrict__ scales,
        const uint4* __restrict__ xf4,
        const float* __restrict__ xsumT,
        const float* __restrict__ midT,
        const float* __restrict__ loraB,
        float* __restrict__ out) {
    const int tid  = threadIdx.x;
    const int m    = tid >> 6;             // wave = M-tile 0..3
    const int lane = tid & 63;
    const int n    = lane & 15;
    const int quad = lane >> 4;
    const int col0 = blockIdx.x * BN;

    const uint4*    xfw = xf4 + (size_t)m * 128 * 64 + lane;
    const uint32_t* qwc = qw + col0 + n;

    float4v acc[2];
    acc[0] = (float4v){0.f, 0.f, 0.f, 0.f};
    acc[1] = (float4v){0.f, 0.f, 0.f, 0.f};

    uint32_t B[4][8];                      // B ring, depth 4 (HBM latency)
    uint4    A[2][4];                      // A ring, depth 2 (L2-hot)
    float4   XS[2];
    float    S0[2], S1[2];
    uint32_t Z0[2], Z1[2];

    LOADB(0, 0); LOADB(1, 1); LOADB(2, 2); LOADB(3, 3);
    LOADA(0, 0); LOADA(1, 1);

    #pragma unroll 4
    for (int g = 0; g < NG; ++g) {
        const int sb = g & 3, sa = g & 1;
        COMPUTE(sa, sb);
        int gb = g + 4; if (gb > NG - 1) gb = NG - 1;   // clamped tail refills
        int ga = g + 2; if (ga > NG - 1) ga = NG - 1;   // (never consumed)
        LOADB(sb, gb);
        LOADA(sa, ga);
    }

    // LoRA epilogue: out = acc + 2 * (mid @ loraB^T); midT/loraB are L2-hot
    #pragma unroll
    for (int nh = 0; nh < 2; ++nh) {
        const int col = col0 + nh * 16 + n;
        float4 lb[4];
        const float4* lbp = (const float4*)(loraB + (size_t)col * RANK);
        #pragma unroll
        for (int i = 0; i < 4; ++i) lb[i] = lbp[i];
        float4v ls = (float4v){0.f, 0.f, 0.f, 0.f};
        #pragma unroll
        for (int j = 0; j < 16; ++j) {
            const float lbj = ((const float*)lb)[j];
            const float4 mv = *(const float4*)(midT + j * 64 + m * 16 + quad * 4);
            ls[0] = fmaf(mv.x, lbj, ls[0]);
            ls[1] = fmaf(mv.y, lbj, ls[1]);
            ls[2] = fmaf(mv.z, lbj, ls[2]);
            ls[3] = fmaf(mv.w, lbj, ls[3]);
        }
        #pragma unroll
        for (int r = 0; r < 4; ++r) {
            const int t = m * 16 + quad * 4 + r;
            out[(size_t)t * OUT_F + col] = acc[nh][r] + LORA_SCALE * ls[r];
        }
    }
}

// ---------------------------------------------------------------------------
extern "C" void kernel_launch(void* const* d_in, const int* in_sizes, int n_in,
                              void* d_out, int out_size, void* d_ws, size_t ws_size,
                              hipStream_t stream) {
    const float*    x      = (const float*)d_in[0];
    const uint32_t* qw     = (const uint32_t*)d_in[1];
    const uint32_t* qz     = (const uint32_t*)d_in[2];
    const float*    scales = (const float*)d_in[3];
    const float*    loraA  = (const float*)d_in[4];
    const float*    loraB  = (const float*)d_in[5];
    float* out = (float*)d_out;

    // ws layout: xf bf16-fragments [4][128][64] uint4 (512 KB) | xsumT | midT
    uint4* xf4   = (uint4*)d_ws;
    float* xsumT = (float*)((char*)d_ws + (size_t)TOKENS * IN_F * 2);
    float* midT  = xsumT + NG * TOKENS;

    prep_kernel<<<TOKENS, 256, 0, stream>>>(x, loraA, xf4, xsumT, midT);
    main_kernel<<<OUT_F / BN, 256, 0, stream>>>(qw, qz, scales, xf4, xsumT, midT, loraB, out);
}

// Round 8
// 107.171 us; speedup vs baseline: 1.0764x; 1.0764x over previous
//
#include <hip/hip_runtime.h>
#include <stdint.h>

// Problem constants (fixed by setup_inputs)
#define TOKENS 64
#define IN_F   4096
#define OUT_F  11008
#define RANK   16
#define GS     128
#define NG     32
#define ZCOLS  (OUT_F / 8)
#define LORA_SCALE 2.0f

using short8  = __attribute__((ext_vector_type(8))) short;
using float4v = __attribute__((ext_vector_type(4))) float;

// round-to-nearest-even fp32 -> bf16 bits; also returns the rounded-back fp32
static __device__ inline uint16_t f2bf(float f, float* back) {
    uint32_t u = __float_as_uint(f);
    uint32_t r = (u + 0x7FFFu + ((u >> 16) & 1u)) >> 16;
    *back = __uint_as_float(r << 16);
    return (uint16_t)r;
}

// ---------------------------------------------------------------------------
// K1: per token t (64 blocks):
//   xf (MFMA-fragment order) = bf16(x)  — xf4[(mt*128 + kchunk)*64 + quad*16 + n]
//   xsumT[g][t] = sum over group g of bf16-rounded x   (GPTQ zero fold)
//   midT[j][t]  = sum_k x[t][k] * lora_A[j][k]         (fp32 LoRA mid)
// ---------------------------------------------------------------------------
__global__ __launch_bounds__(256) void prep_kernel(
        const float* __restrict__ x,
        const float* __restrict__ loraA,
        uint4* __restrict__ xf4,
        float* __restrict__ xsumT,
        float* __restrict__ midT) {
    __shared__ float redg[256];
    __shared__ float redm[4][16];
    const int t    = blockIdx.x;
    const int tid  = threadIdx.x;
    const int lane = tid & 63;
    const int wv   = tid >> 6;

    float4 xv[4];
    const float4* xp = (const float4*)(x + (size_t)t * IN_F + tid * 16);
    #pragma unroll
    for (int i = 0; i < 4; ++i) xv[i] = xp[i];

    union { uint16_t u[16]; uint4 q[2]; } ob;
    float s = 0.f;
    #pragma unroll
    for (int i = 0; i < 4; ++i) {
        float b;
        ob.u[i * 4 + 0] = f2bf(xv[i].x, &b); s += b;
        ob.u[i * 4 + 1] = f2bf(xv[i].y, &b); s += b;
        ob.u[i * 4 + 2] = f2bf(xv[i].z, &b); s += b;
        ob.u[i * 4 + 3] = f2bf(xv[i].w, &b); s += b;
    }
    // scatter into fragment order
    {
        const int mm = t >> 4, nn = t & 15;
        const int kchunk = tid >> 1;
        #pragma unroll
        for (int i = 0; i < 2; ++i) {
            const int qd = (tid * 2 + i) & 3;
            xf4[(size_t)((mm * 128 + kchunk) * 64 + qd * 16 + nn)] = ob.q[i];
        }
    }
    redg[tid] = s;

    // LoRA mid partials
    float pj[16];
    #pragma unroll
    for (int j = 0; j < 16; ++j) {
        const float4* ap = (const float4*)(loraA + (size_t)j * IN_F + tid * 16);
        float ps = 0.f;
        #pragma unroll
        for (int i = 0; i < 4; ++i) {
            float4 a = ap[i];
            ps += a.x * xv[i].x + a.y * xv[i].y + a.z * xv[i].z + a.w * xv[i].w;
        }
        pj[j] = ps;
    }
    #pragma unroll
    for (int j = 0; j < 16; ++j) {
        #pragma unroll
        for (int off = 32; off; off >>= 1) pj[j] += __shfl_down(pj[j], off);
    }
    if (lane == 0) {
        #pragma unroll
        for (int j = 0; j < 16; ++j) redm[wv][j] = pj[j];
    }
    __syncthreads();
    if (tid < NG) {
        float g = 0.f;
        #pragma unroll
        for (int i = 0; i < 8; ++i) g += redg[tid * 8 + i];
        xsumT[tid * TOKENS + t] = g;
    }
    if (tid < 16)
        midT[tid * TOKENS + t] = redm[0][tid] + redm[1][tid] + redm[2][tid] + redm[3][tid];
}

// ---------------------------------------------------------------------------
// K2: out[t][o] = LORA_SCALE * sum_j midT[j][t] * loraB[o][j]
// Pre-initializes out (poisoned by harness) before K3's split-K atomics.
// ---------------------------------------------------------------------------
__global__ __launch_bounds__(256) void lora_out_kernel(
        const float* __restrict__ midT,
        const float* __restrict__ loraB,
        float* __restrict__ out) {
    const int gid = blockIdx.x * 256 + threadIdx.x;
    const int t = gid / OUT_F;
    const int o = gid - t * OUT_F;
    const float4* b4 = (const float4*)(loraB + (size_t)o * RANK);
    float s = 0.f;
    #pragma unroll
    for (int i = 0; i < 4; ++i) {
        float4 b = b4[i];
        s += b.x * midT[(i * 4 + 0) * TOKENS + t];
        s += b.y * midT[(i * 4 + 1) * TOKENS + t];
        s += b.z * midT[(i * 4 + 2) * TOKENS + t];
        s += b.w * midT[(i * 4 + 3) * TOKENS + t];
    }
    out[gid] = s * LORA_SCALE;
}

// ---------------------------------------------------------------------------
// K3: GPTQ-dequant GEMM, split-K=4, zero LDS / zero barriers.
// Block 256 = 4 waves: wave = (M-half mh: 2 M-tiles = 32 tokens) x
// (col-slice cs: 32 cols), over kseg's 8 groups. blockIdx.x = colblk*4 + kseg.
// Same-mh waves share A via L1; same-cs waves share B via L1.
// Each dequanted B word feeds 2 MFMAs (both M-tiles). Depth-2 rings.
// Partials combined with fp32 atomicAdd onto LoRA-initialized out.
// ---------------------------------------------------------------------------
#define LOADG(st, g) do {                                                       \
    _Pragma("unroll")                                                           \
    for (int mt = 0; mt < 2; ++mt)                                              \
        _Pragma("unroll")                                                       \
        for (int ks = 0; ks < 4; ++ks)                                          \
            A[st][mt * 4 + ks] =                                                \
                xf4[(size_t)(((mh * 2 + mt) * 128 + (g) * 4 + ks) * 64) + lane];\
    _Pragma("unroll")                                                           \
    for (int ks = 0; ks < 4; ++ks)                                              \
        _Pragma("unroll")                                                       \
        for (int nh = 0; nh < 2; ++nh)                                          \
            B[st][ks * 2 + nh] =                                                \
                qwc[(size_t)((g) * 16 + ks * 4 + quad) * OUT_F + nh * 16];      \
    _Pragma("unroll")                                                           \
    for (int mt = 0; mt < 2; ++mt)                                              \
        XS[st][mt] = *(const float4*)(xsumT + (g) * 64 +                        \
                                      (mh * 2 + mt) * 16 + quad * 4);           \
    _Pragma("unroll")                                                           \
    for (int nh = 0; nh < 2; ++nh) {                                            \
        S[st][nh] = scales[(size_t)(g) * OUT_F + col0 + nh * 16 + n];           \
        Z[st][nh] = qz[(size_t)(g) * ZCOLS + ((col0 + nh * 16 + n) >> 3)];      \
    }                                                                           \
} while (0)

#define COMPUTEG(st) do {                                                       \
    float4v accg[2][2];                                                         \
    _Pragma("unroll")                                                           \
    for (int mt = 0; mt < 2; ++mt)                                              \
        _Pragma("unroll")                                                       \
        for (int nh = 0; nh < 2; ++nh)                                          \
            accg[mt][nh] = (float4v){0.f, 0.f, 0.f, 0.f};                       \
    _Pragma("unroll")                                                           \
    for (int ks = 0; ks < 4; ++ks) {                                            \
        union { uint4 u; short8 s; } af0, af1;                                  \
        af0.u = A[st][ks];                                                      \
        af1.u = A[st][4 + ks];                                                  \
        _Pragma("unroll")                                                       \
        for (int nh = 0; nh < 2; ++nh) {                                        \
            uint32_t q  = B[st][ks * 2 + nh];                                   \
            uint32_t lo = q & 0x0F0F0F0Fu;                                      \
            uint32_t hi = (q >> 4) & 0x0F0F0F0Fu;                               \
            union { uint32_t u32[4]; short8 s8; } bf;                           \
            _Pragma("unroll")                                                   \
            for (int i = 0; i < 4; ++i)                                         \
                bf.u32[i] = __builtin_amdgcn_perm(hi, lo,                       \
                                0x0C040C00u + i * 0x00010001u) | 0x43004300u;   \
            accg[0][nh] = __builtin_amdgcn_mfma_f32_16x16x32_bf16(af0.s, bf.s8, \
                                                            accg[0][nh], 0, 0, 0);\
            accg[1][nh] = __builtin_amdgcn_mfma_f32_16x16x32_bf16(af1.s, bf.s8, \
                                                            accg[1][nh], 0, 0, 0);\
        }                                                                       \
    }                                                                           \
    _Pragma("unroll")                                                           \
    for (int nh = 0; nh < 2; ++nh) {                                            \
        const float zoff = (float)(((Z[st][nh] >>                               \
                        (((col0 + nh * 16 + n) & 7) * 4)) & 0xFu) + 129u);      \
        const float scl = S[st][nh];                                            \
        _Pragma("unroll")                                                       \
        for (int mt = 0; mt < 2; ++mt) {                                        \
            const float xr[4] = {XS[st][mt].x, XS[st][mt].y,                    \
                                 XS[st][mt].z, XS[st][mt].w};                   \
            _Pragma("unroll")                                                   \
            for (int r = 0; r < 4; ++r)                                         \
                acc[mt][nh][r] = fmaf(scl, fmaf(-zoff, xr[r],                   \
                                      accg[mt][nh][r]), acc[mt][nh][r]);        \
        }                                                                       \
    }                                                                           \
} while (0)

__global__ __launch_bounds__(256, 3) void main_kernel(
        const uint32_t* __restrict__ qw,
        const uint32_t* __restrict__ qz,
        const float* __restrict__ scales,
        const uint4* __restrict__ xf4,
        const float* __restrict__ xsumT,
        float* __restrict__ out) {
    const int tid  = threadIdx.x;
    const int wv   = tid >> 6;
    const int lane = tid & 63;
    const int n    = lane & 15;
    const int quad = lane >> 4;
    const int mh   = wv & 1;               // M-half: tiles {2mh, 2mh+1}
    const int cs   = wv >> 1;              // col-slice within block
    const int colblk = blockIdx.x >> 2;
    const int kseg   = blockIdx.x & 3;
    const int col0   = colblk * 64 + cs * 32;
    const int g0     = kseg * 8;

    const uint32_t* qwc = qw + col0 + n;

    float4v acc[2][2];
    #pragma unroll
    for (int mt = 0; mt < 2; ++mt)
        #pragma unroll
        for (int nh = 0; nh < 2; ++nh)
            acc[mt][nh] = (float4v){0.f, 0.f, 0.f, 0.f};

    uint4    A[2][8];
    uint32_t B[2][8];
    float4   XS[2][2];
    float    S[2][2];
    uint32_t Z[2][2];

    LOADG(0, g0);
    LOADG(1, g0 + 1);
    #pragma unroll
    for (int gi = 0; gi < 8; ++gi) {
        const int st = gi & 1;
        COMPUTEG(st);
        int gl = gi + 2; if (gl > 7) gl = 7;   // clamped tail refill (unused)
        LOADG(st, g0 + gl);
    }

    // split-K combine: 4 partials per output element
    #pragma unroll
    for (int mt = 0; mt < 2; ++mt)
        #pragma unroll
        for (int nh = 0; nh < 2; ++nh)
            #pragma unroll
            for (int r = 0; r < 4; ++r) {
                const int t = (mh * 2 + mt) * 16 + quad * 4 + r;
                atomicAdd(out + (size_t)t * OUT_F + col0 + nh * 16 + n,
                          acc[mt][nh][r]);
            }
}

// ---------------------------------------------------------------------------
extern "C" void kernel_launch(void* const* d_in, const int* in_sizes, int n_in,
                              void* d_out, int out_size, void* d_ws, size_t ws_size,
                              hipStream_t stream) {
    const float*    x      = (const float*)d_in[0];
    const uint32_t* qw     = (const uint32_t*)d_in[1];
    const uint32_t* qz     = (const uint32_t*)d_in[2];
    const float*    scales = (const float*)d_in[3];
    const float*    loraA  = (const float*)d_in[4];
    const float*    loraB  = (const float*)d_in[5];
    float* out = (float*)d_out;

    // ws layout: xf bf16-fragments [4][128][64] uint4 (512 KB) | xsumT | midT
    uint4* xf4   = (uint4*)d_ws;
    float* xsumT = (float*)((char*)d_ws + (size_t)TOKENS * IN_F * 2);
    float* midT  = xsumT + NG * TOKENS;

    prep_kernel<<<TOKENS, 256, 0, stream>>>(x, loraA, xf4, xsumT, midT);
    lora_out_kernel<<<(TOKENS * OUT_F) / 256, 256, 0, stream>>>(midT, loraB, out);
    main_kernel<<<(OUT_F / 64) * 4, 256, 0, stream>>>(qw, qz, scales, xf4, xsumT, out);
}